// Round 6
// baseline (725.331 us; speedup 1.0000x reference)
//
#include <hip/hip_runtime.h>
#include <math.h>

#define NPTS 65536
#define EPSV 1e-5f
#define B1G  256    // kernel-1 grid (proven ws layout)
#define B3G  1024   // kernel-3 grid (64 n per block -> 4 blocks/CU)

// workspace float offsets
#define OFF_P1  0                      // B1G*65 ; reused by k2c: W2S[128][128]+cb[128]
#define OFF_S1  (B1G*65)               // 256 : scale1[128], shift1[128]
#define OFF_P2  (OFF_S1+256)           // B3G*128
#define OFF_S2  (OFF_P2+B3G*128)       // 128 : scale2[64], shift2[64]
#define OFF_PRE (OFF_S2+128)           // NPTS*64

typedef unsigned int u32;
typedef short v8s __attribute__((ext_vector_type(8)));   // 8 bf16 = 4 VGPRs (MFMA A/B frag)
typedef float v4f __attribute__((ext_vector_type(4)));   // MFMA C/D frag

union F8 { v8s v; u32 u[4]; unsigned short s[8]; };

__device__ __forceinline__ u32 f2bf(float f){
  u32 u = __float_as_uint(f);
  return (u + 0x7fffu + ((u>>16)&1u)) >> 16;   // RNE to bf16 (init-path only)
}
__device__ __forceinline__ float bf2f(unsigned short s){ return __uint_as_float(((u32)s)<<16); }
// HW packed convert: lo=RNE(a), hi=RNE(b). 1 VALU op.
__device__ __forceinline__ u32 packbf(float a, float b){
  u32 r; asm("v_cvt_pk_bf16_f32 %0, %1, %2" : "=v"(r) : "v"(a), "v"(b)); return r;
}
__device__ __forceinline__ float rcpf(float x){
  float r; asm("v_rcp_f32 %0, %1" : "=v"(r) : "v"(x)); return r;
}
// s_h column interleave: phys short p -> logical h channel
__device__ __forceinline__ int chmap(int p){ return 32*(p>>5) + ((p&31)>>1) + 16*(p&1); }
// s_ft column interleave: phys short p -> logical feat channel (lo=16w+c, hi=64+16w+c)
__device__ __forceinline__ int chmap2(int p){ return 16*(p>>5) + ((p&31)>>1) + 64*(p&1); }

// ---------------- kernel 1: Gram-matrix stats over all N*K rows -------------
// (256,1): allow full VGPR so the 65 accumulators never spill to scratch.
__global__ __launch_bounds__(256,1) void k1_stats(const float* __restrict__ p, float* __restrict__ part1){
  int tid = blockIdx.x*256 + threadIdx.x;
  float M[55]; float s[10];
  #pragma unroll
  for(int i=0;i<55;i++) M[i]=0.f;
  #pragma unroll
  for(int i=0;i<10;i++) s[i]=0.f;
  for(int it=0; it<16; ++it){
    int r = it*65536 + tid;
    int n = r >> 4;
    int kk = r & 15;
    const float* pn = p + (size_t)n*48;
    float cx=pn[0], cy=pn[1], cz=pn[2];
    float ax=pn[kk*3+0], ay=pn[kk*3+1], az=pn[kk*3+2];
    float dx=cx-ax, dy=cy-ay, dz=cz-az;
    float dd = sqrtf(dx*dx+dy*dy+dz*dz);
    float c[10]={cx,cy,cz,ax,ay,az,dx,dy,dz,dd};
    #pragma unroll
    for(int i=0;i<10;i++) s[i]+=c[i];
    int idx=0;
    #pragma unroll
    for(int i=0;i<10;i++){
      #pragma unroll
      for(int j=i;j<10;j++){
        M[idx] = fmaf(c[i],c[j],M[idx]);
        idx++;
      }
    }
  }
  #pragma unroll
  for(int i=0;i<10;i++){
    for(int off=32; off>0; off>>=1) s[i] += __shfl_down(s[i], off, 64);
  }
  #pragma unroll
  for(int i=0;i<55;i++){
    for(int off=32; off>0; off>>=1) M[i] += __shfl_down(M[i], off, 64);
  }
  __shared__ float sm[4][65];
  int lane = threadIdx.x & 63, w = threadIdx.x >> 6;
  if(lane==0){
    #pragma unroll
    for(int i=0;i<10;i++) sm[w][i]=s[i];
    #pragma unroll
    for(int i=0;i<55;i++) sm[w][10+i]=M[i];
  }
  __syncthreads();
  if(threadIdx.x<65){
    float v = sm[0][threadIdx.x]+sm[1][threadIdx.x]+sm[2][threadIdx.x]+sm[3][threadIdx.x];
    part1[blockIdx.x*65 + threadIdx.x] = v;
  }
}

// ---------------- kernel 2: finalize BN1 scale/shift ------------------------
__device__ __forceinline__ int tri_idx(int i,int j){
  int a = i<j? i : j;
  int b = i<j? j : i;
  return 10*a - (a*(a-1))/2 + (b-a);
}
__global__ __launch_bounds__(256) void k2_fin(const float* __restrict__ part1, const float* __restrict__ w1,
                       const float* __restrict__ g1, const float* __restrict__ be1,
                       float* __restrict__ stats1){
  __shared__ float P[4][65];
  __shared__ float S[65];
  int t = threadIdx.x; // 256
  for(int idx=t; idx<260; idx+=256){
    int seg = idx/65, v = idx - seg*65;
    float a=0.f;
    for(int b=seg; b<B1G; b+=4) a += part1[b*65+v];
    P[seg][v]=a;
  }
  __syncthreads();
  if(t<65) S[t] = P[0][t]+P[1][t]+P[2][t]+P[3][t];
  __syncthreads();
  if(t<128){
    float wc[10];
    #pragma unroll
    for(int c=0;c<10;c++) wc[c]=w1[c*128+t];
    float md=0.f;
    #pragma unroll
    for(int c=0;c<10;c++) md += S[c]*wc[c];
    const float invR = 1.0f/(float)(NPTS*16);
    md *= invR;
    float q=0.f;
    #pragma unroll
    for(int i=0;i<10;i++){
      float ti=0.f;
      #pragma unroll
      for(int j=0;j<10;j++) ti += S[10+tri_idx(i,j)]*wc[j];
      q = fmaf(ti, wc[i], q);
    }
    q *= invR;
    float var = q - md*md;
    float sc = g1[t]*rsqrtf(var+EPSV);
    float sh = be1[t] - md*sc;            // b1 cancels inside BN
    stats1[t]=sc;
    stats1[128+t]=sh;
  }
}

// ---------------- kernel 2c: W2S = w2 @ ws_top, cb = b2 @ ws_top ------------
// Writes into the part1 region (16512 <= 16640 floats) AFTER k2 consumed it.
// Stream order k2 -> k2c -> k3 makes this race-free with zero ws growth.
__global__ __launch_bounds__(256) void k2c_w2s(const float* __restrict__ w2, const float* __restrict__ wsm,
                        const float* __restrict__ b2, float* __restrict__ w2s){
  int gid = blockIdx.x*256 + threadIdx.x;   // 64 blocks -> 16384 threads
  int k = gid >> 7, e = gid & 127;
  float a = 0.f;
  for(int d=0; d<64; d++) a = fmaf(w2[k*64+d], wsm[d*128+e], a);
  w2s[k*128+e] = a;
  if(gid < 128){
    float cbv = 0.f;
    for(int d=0; d<64; d++) cbv = fmaf(b2[d], wsm[d*128+gid], cbv);
    w2s[16384+gid] = cbv;
  }
}

// ---------------- kernel 3: MFMA block-cooperative pipeline -----------------
// 2 barriers/round (was 3): logits = h@W2S + x@ws_bot + cb, so p_c never
// round-trips through LDS. Wave w owns logit chs (16w+c, 64+16w+c); the lo
// channel equals the lane's own p_c accumulator channel -> value pooling uses
// fp32 p_c from registers. x and per-lane p coords double-buffered in regs.
__global__ __launch_bounds__(256,4) void k3_main(
    const float* __restrict__ p, const float* __restrict__ x,
    const float* __restrict__ w2, const float* __restrict__ b2,
    const float* __restrict__ wsm, const float* __restrict__ wo,
    const float* __restrict__ w1, const float* __restrict__ stats1,
    const float* __restrict__ w2s,
    float* __restrict__ pre, float* __restrict__ part2)
{
  __shared__ unsigned short s_h [4][16][136];   // h bf16 (interleaved cols), 272B row stride
  __shared__ unsigned short s_x [4][16][72];    // x bf16 (natural cols 0..63), 144B row stride
  __shared__ unsigned short s_ft[16][136];      // feat bf16 (chmap2-interleaved cols)

  const int tid  = threadIdx.x;
  const int w    = tid>>6;
  const int lane = tid&63;
  const int q    = lane>>4;
  const int c    = lane&15;

  // ---- register-resident B fragments (k = kk*32 + q*8 + j) ----------------
  v8s Bw1[2], Bw2[4], BSlo[4], BShi[4], Bbl[2], Bbh[2];
  #pragma unroll
  for(int t=0;t<2;t++){
    F8 f;
    #pragma unroll
    for(int j=0;j<8;j++){
      int k = q*8+j;
      f.s[j] = (unsigned short)(k<10 ? f2bf(w1[k*128 + 32*w + 16*t + c]) : 0);
    }
    Bw1[t]=f.v;
  }
  #pragma unroll
  for(int kk=0;kk<4;kk++){                      // rows chmap'd: s_h is col-interleaved
    F8 f, g, h2;
    #pragma unroll
    for(int j=0;j<8;j++){
      int row = chmap(kk*32+q*8+j);
      f.s[j]  = (unsigned short)f2bf(w2 [row*64  + 16*w + c]);
      g.s[j]  = (unsigned short)f2bf(w2s[row*128 + 16*w + c]);
      h2.s[j] = (unsigned short)f2bf(w2s[row*128 + 64 + 16*w + c]);
    }
    Bw2[kk]=f.v; BSlo[kk]=g.v; BShi[kk]=h2.v;
  }
  #pragma unroll
  for(int kk=0;kk<2;kk++){                      // x-part of ws: natural rows
    F8 f, g;
    #pragma unroll
    for(int j=0;j<8;j++){
      int row = 64 + kk*32+q*8+j;
      f.s[j] = (unsigned short)f2bf(wsm[row*128 + 16*w + c]);
      g.s[j] = (unsigned short)f2bf(wsm[row*128 + 64 + 16*w + c]);
    }
    Bbl[kk]=f.v; Bbh[kk]=g.v;
  }
  const float sc1a = stats1[32*w+c],    sh1a = stats1[128+32*w+c];
  const float sc1b = stats1[32*w+16+c], sh1b = stats1[128+32*w+16+c];
  const float b2v  = b2[16*w+c];
  const float cb_lo = w2s[16384 + 16*w+c];
  const float cb_hi = w2s[16384 + 64+16*w+c];

  float a_s=0.f, a_q=0.f;
  const int base0 = blockIdx.x*64;

  // ---- x staging: per-thread LDS destinations are round-invariant ---------
  unsigned short *xd0, *xd1, *xd2, *xd3;
  {
    int f;
    f = tid;       xd0 = &s_x[f>>8][(f&255)>>4][4*(f&15)];
    f = tid+256;   xd1 = &s_x[f>>8][(f&255)>>4][4*(f&15)];
    f = tid+512;   xd2 = &s_x[f>>8][(f&255)>>4][4*(f&15)];
    f = tid+768;   xd3 = &s_x[f>>8][(f&255)>>4][4*(f&15)];
  }
  // prologue: round-0 x and p (per-lane point coords) into registers
  float4 xr0, xr1, xr2, xr3;
  float pax0,pay0,paz0, pax1,pay1,paz1, pax2,pay2,paz2, pax3,pay3,paz3;
  {
    const float4* xg = (const float4*)(x + (size_t)base0*1024);
    xr0 = xg[tid]; xr1 = xg[tid+256]; xr2 = xg[tid+512]; xr3 = xg[tid+768];
    const float* pn0 = p + (size_t)(base0+0)*48;
    const float* pn1 = p + (size_t)(base0+1)*48;
    const float* pn2 = p + (size_t)(base0+2)*48;
    const float* pn3 = p + (size_t)(base0+3)*48;
    pax0=pn0[3*c]; pay0=pn0[3*c+1]; paz0=pn0[3*c+2];
    pax1=pn1[3*c]; pay1=pn1[3*c+1]; paz1=pn1[3*c+2];
    pax2=pn2[3*c]; pay2=pn2[3*c+1]; paz2=pn2[3*c+2];
    pax3=pn3[3*c]; pay3=pn3[3*c+1]; paz3=pn3[3*c+2];
  }

  for(int r=0;r<16;++r){
    // ---- write buffered x regs -> s_x --------------------------------------
    *(uint2*)xd0 = make_uint2(packbf(xr0.x,xr0.y), packbf(xr0.z,xr0.w));
    *(uint2*)xd1 = make_uint2(packbf(xr1.x,xr1.y), packbf(xr1.z,xr1.w));
    *(uint2*)xd2 = make_uint2(packbf(xr2.x,xr2.y), packbf(xr2.z,xr2.w));
    *(uint2*)xd3 = make_uint2(packbf(xr3.x,xr3.y), packbf(xr3.z,xr3.w));

    // ---- stage1: h = concat@w1 -> BN1 -> relu -> s_h (bf16, interleaved) --
    #pragma unroll
    for(int n0=0;n0<4;n0++){
      float ax = n0==0?pax0 : n0==1?pax1 : n0==2?pax2 : pax3;
      float ay = n0==0?pay0 : n0==1?pay1 : n0==2?pay2 : pay3;
      float az = n0==0?paz0 : n0==1?paz1 : n0==2?paz2 : paz3;
      float cx = __shfl(ax, 0, 64);     // lane c=0 holds the center point
      float cy = __shfl(ay, 0, 64);
      float cz = __shfl(az, 0, 64);
      float dx=cx-ax, dy=cy-ay, dz=cz-az;
      float dd=sqrtf(dx*dx+dy*dy+dz*dz);
      u32 pk01=packbf(cx,cy), pk23=packbf(cz,ax), pk45=packbf(ay,az),
          pk67=packbf(dx,dy), pk89=packbf(dz,dd);
      F8 fa;
      fa.u[0] = q==0 ? pk01 : (q==1 ? pk89 : 0u);
      fa.u[1] = q==0 ? pk23 : 0u;
      fa.u[2] = q==0 ? pk45 : 0u;
      fa.u[3] = q==0 ? pk67 : 0u;
      v4f z={0.f,0.f,0.f,0.f};
      v4f d0 = __builtin_amdgcn_mfma_f32_16x16x32_bf16(fa.v, Bw1[0], z, 0,0,0);
      v4f d1 = __builtin_amdgcn_mfma_f32_16x16x32_bf16(fa.v, Bw1[1], z, 0,0,0);
      #pragma unroll
      for(int i=0;i<4;i++){
        float v0 = fmaxf(0.f, fmaf(d0[i], sc1a, sh1a));
        float v1 = fmaxf(0.f, fmaf(d1[i], sc1b, sh1b));
        *(u32*)&s_h[n0][4*q+i][32*w+2*c] = packbf(v0, v1);
      }
    }

    // ---- issue next round's x and p loads (regs free after consumption) ---
    if(r<15){
      const int nbase = base0 + 4*r + 4;
      const float4* xg = (const float4*)(x + (size_t)nbase*1024);
      xr0 = xg[tid]; xr1 = xg[tid+256]; xr2 = xg[tid+512]; xr3 = xg[tid+768];
      const float* pn0 = p + (size_t)(nbase+0)*48;
      const float* pn1 = p + (size_t)(nbase+1)*48;
      const float* pn2 = p + (size_t)(nbase+2)*48;
      const float* pn3 = p + (size_t)(nbase+3)*48;
      pax0=pn0[3*c]; pay0=pn0[3*c+1]; paz0=pn0[3*c+2];
      pax1=pn1[3*c]; pay1=pn1[3*c+1]; paz1=pn1[3*c+2];
      pax2=pn2[3*c]; pay2=pn2[3*c+1]; paz2=pn2[3*c+2];
      pax3=pn3[3*c]; pay3=pn3[3*c+1]; paz3=pn3[3*c+2];
    }
    __syncthreads();   // barrier1: s_h + s_x ready

    // ---- phase A: p_c, logits, softmax, pool -> s_ft ----------------------
    #pragma unroll
    for(int n0=0;n0<4;n0++){
      const v8s* Ah = (const v8s*)&s_h[n0][c][0];
      const v8s* Ax = (const v8s*)&s_x[n0][c][0];
      v4f acc={0.f,0.f,0.f,0.f}, llo={0.f,0.f,0.f,0.f}, lhi={0.f,0.f,0.f,0.f};
      #pragma unroll
      for(int kk=0;kk<4;kk++){
        v8s a = Ah[kk*4+q];
        acc = __builtin_amdgcn_mfma_f32_16x16x32_bf16(a, Bw2[kk],  acc, 0,0,0);
        llo = __builtin_amdgcn_mfma_f32_16x16x32_bf16(a, BSlo[kk], llo, 0,0,0);
        lhi = __builtin_amdgcn_mfma_f32_16x16x32_bf16(a, BShi[kk], lhi, 0,0,0);
      }
      #pragma unroll
      for(int kk=0;kk<2;kk++){
        v8s a = Ax[kk*4+q];
        llo = __builtin_amdgcn_mfma_f32_16x16x32_bf16(a, Bbl[kk], llo, 0,0,0);
        lhi = __builtin_amdgcn_mfma_f32_16x16x32_bf16(a, Bbh[kk], lhi, 0,0,0);
      }
      float se_lo=0.f, se_hi=0.f, fe_lo=0.f, fe_hi=0.f;
      #pragma unroll
      for(int i=0;i<4;i++){
        float pcv = acc[i] + b2v;                       // fp32 p_c, own channel
        float xv  = bf2f(s_x[n0][4*q+i][16*w+c]);       // x value, own channel
        float El = __expf(llo[i] + cb_lo);
        float Eh = __expf(lhi[i] + cb_hi);
        se_lo += El; fe_lo = fmaf(El, pcv, fe_lo);
        se_hi += Eh; fe_hi = fmaf(Eh, xv,  fe_hi);
      }
      se_lo += __shfl_xor(se_lo,16); se_lo += __shfl_xor(se_lo,32);
      se_hi += __shfl_xor(se_hi,16); se_hi += __shfl_xor(se_hi,32);
      fe_lo += __shfl_xor(fe_lo,16); fe_lo += __shfl_xor(fe_lo,32);
      fe_hi += __shfl_xor(fe_hi,16); fe_hi += __shfl_xor(fe_hi,32);
      if(q==0){
        const int slot = (r&3)*4 + n0;
        *(u32*)&s_ft[slot][32*w+2*c] = packbf(fe_lo*rcpf(se_lo), fe_hi*rcpf(se_hi));
      }
    }
    __syncthreads();   // barrier2: s_ft ready; s_h/s_x free for next round

    // ---- stage5: out = feat@wo for 16 buffered n (every 4 rounds) ---------
    if((r&3)==3){
      v8s Bwo[4];
      #pragma unroll
      for(int kk=0;kk<4;kk++){                  // rows chmap2'd (s_ft layout); L2-hot
        F8 f;
        #pragma unroll
        for(int j=0;j<8;j++) f.s[j]=(unsigned short)f2bf(wo[chmap2(kk*32+q*8+j)*64 + 16*w + c]);
        Bwo[kk]=f.v;
      }
      const v8s* Ar = (const v8s*)&s_ft[c][0];
      v4f o={0.f,0.f,0.f,0.f};
      #pragma unroll
      for(int kk=0;kk<4;kk++)
        o = __builtin_amdgcn_mfma_f32_16x16x32_bf16(Ar[kk*4+q], Bwo[kk], o, 0,0,0);
      const int nb16 = base0 + (r>>2)*16;
      #pragma unroll
      for(int i=0;i<4;i++){
        float val = o[i];
        pre[(size_t)(nb16 + 4*q + i)*64 + 16*w + c] = val;
        a_s += val;
        a_q = fmaf(val,val,a_q);
      }
    }
  }

  // ---- BN2 partials: reduce over quads (same d = 16w+c across q) ----------
  a_s += __shfl_xor(a_s, 16, 64); a_s += __shfl_xor(a_s, 32, 64);
  a_q += __shfl_xor(a_q, 16, 64); a_q += __shfl_xor(a_q, 32, 64);
  if(q==0){
    part2[blockIdx.x*128 + 16*w + c]      = a_s;
    part2[blockIdx.x*128 + 64 + 16*w + c] = a_q;
  }
}

// ---------------- kernel 4: finalize BN2 scale/shift ------------------------
__global__ __launch_bounds__(1024) void k4_fin(const float* __restrict__ part2, const float* __restrict__ g2,
                       const float* __restrict__ be2, float* __restrict__ stats2){
  __shared__ float sm[16][128];
  int t = threadIdx.x; // 1024
  int d = t & 63, seg = t >> 6;   // 16 segs
  float s=0.f, qq=0.f;
  for(int i=0;i<B3G/16;i++){
    int b = seg + 16*i;
    s  += part2[b*128+d];
    qq += part2[b*128+64+d];
  }
  sm[seg][d]    = s;
  sm[seg][64+d] = qq;
  __syncthreads();
  if(t<64){
    float S=0.f, Q=0.f;
    #pragma unroll
    for(int k=0;k<16;k++){ S += sm[k][t]; Q += sm[k][64+t]; }
    float mu  = S/(float)NPTS;
    float var = Q/(float)NPTS - mu*mu;
    float sc = g2[t]*rsqrtf(var+EPSV);
    float sh = be2[t] - mu*sc;            // bo cancels inside BN
    stats2[t]=sc;
    stats2[64+t]=sh;
  }
}

// ---------------- kernel 5: apply BN2 + relu --------------------------------
__global__ __launch_bounds__(256) void k5_apply(const float* __restrict__ pre,
                                                const float* __restrict__ stats2,
                                                float* __restrict__ out){
  int i = blockIdx.x*256 + threadIdx.x;      // float4 index; 1,048,576 total
  float4 v = ((const float4*)pre)[i];
  int d4 = i & 15;
  float4 sc = ((const float4*)stats2)[d4];
  float4 sh = ((const float4*)(stats2+64))[d4];
  float4 o;
  o.x = fmaxf(0.f, fmaf(v.x,sc.x,sh.x));
  o.y = fmaxf(0.f, fmaf(v.y,sc.y,sh.y));
  o.z = fmaxf(0.f, fmaf(v.z,sc.z,sh.z));
  o.w = fmaxf(0.f, fmaf(v.w,sc.w,sh.w));
  ((float4*)out)[i] = o;
}

extern "C" void kernel_launch(void* const* d_in, const int* in_sizes, int n_in,
                              void* d_out, int out_size, void* d_ws, size_t ws_size,
                              hipStream_t stream){
  (void)in_sizes; (void)n_in; (void)out_size; (void)ws_size;
  const float* p   = (const float*)d_in[0];
  const float* x   = (const float*)d_in[1];
  const float* w1  = (const float*)d_in[2];
  // d_in[3] = b1  : cancels inside BN1
  const float* g1  = (const float*)d_in[4];
  const float* be1 = (const float*)d_in[5];
  const float* w2  = (const float*)d_in[6];
  const float* b2  = (const float*)d_in[7];
  const float* wsm = (const float*)d_in[8];
  const float* wo  = (const float*)d_in[9];
  // d_in[10] = bo : cancels inside BN2
  const float* g2  = (const float*)d_in[11];
  const float* be2 = (const float*)d_in[12];

  float* wsf    = (float*)d_ws;
  float* part1  = wsf + OFF_P1;     // reused as W2S/cb after k2
  float* stats1 = wsf + OFF_S1;
  float* part2  = wsf + OFF_P2;
  float* stats2 = wsf + OFF_S2;
  float* pre    = wsf + OFF_PRE;
  float* out    = (float*)d_out;

  k1_stats<<<B1G,256,0,stream>>>(p, part1);
  k2_fin  <<<1,256,0,stream>>>(part1, w1, g1, be1, stats1);
  k2c_w2s <<<64,256,0,stream>>>(w2, wsm, b2, part1);
  k3_main <<<B3G,256,0,stream>>>(p,x,w2,b2,wsm,wo,w1,stats1,part1,pre,part2);
  k4_fin  <<<1,1024,0,stream>>>(part2,g2,be2,stats2);
  k5_apply<<<4096,256,0,stream>>>(pre,stats2,out);
}

// Round 7
// 709.585 us; speedup vs baseline: 1.0222x; 1.0222x over previous
//
#include <hip/hip_runtime.h>
#include <math.h>

#define NPTS 65536
#define EPSV 1e-5f
#define B1G  256    // kernel-1 grid (proven ws layout)
#define B3G  1024   // kernel-3 grid (64 n per block -> 4 blocks/CU)

// workspace float offsets
#define OFF_P1  0                      // B1G*65 ; reused by k2c: W2S[128][128]+cb[128]
#define OFF_S1  (B1G*65)               // 256 : scale1[128], shift1[128]
#define OFF_P2  (OFF_S1+256)           // B3G*128
#define OFF_S2  (OFF_P2+B3G*128)       // 128 : scale2[64], shift2[64]
#define OFF_PRE (OFF_S2+128)           // NPTS*64

typedef unsigned int u32;
typedef short v8s __attribute__((ext_vector_type(8)));   // 8 bf16 = 4 VGPRs (MFMA A/B frag)
typedef float v4f __attribute__((ext_vector_type(4)));   // MFMA C/D frag

union F8 { v8s v; u32 u[4]; unsigned short s[8]; };

__device__ __forceinline__ u32 f2bf(float f){
  u32 u = __float_as_uint(f);
  return (u + 0x7fffu + ((u>>16)&1u)) >> 16;   // RNE to bf16 (init-path only)
}
__device__ __forceinline__ float bf2f(unsigned short s){ return __uint_as_float(((u32)s)<<16); }
// HW packed convert: lo=RNE(a), hi=RNE(b). 1 VALU op.
__device__ __forceinline__ u32 packbf(float a, float b){
  u32 r; asm("v_cvt_pk_bf16_f32 %0, %1, %2" : "=v"(r) : "v"(a), "v"(b)); return r;
}
__device__ __forceinline__ float rcpf(float x){
  float r; asm("v_rcp_f32 %0, %1" : "=v"(r) : "v"(x)); return r;
}
// s_h column interleave: phys short p -> logical h channel
__device__ __forceinline__ int chmap(int p){ return 32*(p>>5) + ((p&31)>>1) + 16*(p&1); }
// s_ft column interleave: phys short p -> logical feat channel (lo=16w+c, hi=64+16w+c)
__device__ __forceinline__ int chmap2(int p){ return 16*(p>>5) + ((p&31)>>1) + 64*(p&1); }

// ---------------- kernel 1: Gram-matrix stats over all N*K rows -------------
__global__ __launch_bounds__(256,1) void k1_stats(const float* __restrict__ p, float* __restrict__ part1){
  int tid = blockIdx.x*256 + threadIdx.x;
  float M[55]; float s[10];
  #pragma unroll
  for(int i=0;i<55;i++) M[i]=0.f;
  #pragma unroll
  for(int i=0;i<10;i++) s[i]=0.f;
  for(int it=0; it<16; ++it){
    int r = it*65536 + tid;
    int n = r >> 4;
    int kk = r & 15;
    const float* pn = p + (size_t)n*48;
    float cx=pn[0], cy=pn[1], cz=pn[2];
    float ax=pn[kk*3+0], ay=pn[kk*3+1], az=pn[kk*3+2];
    float dx=cx-ax, dy=cy-ay, dz=cz-az;
    float dd = sqrtf(dx*dx+dy*dy+dz*dz);
    float c[10]={cx,cy,cz,ax,ay,az,dx,dy,dz,dd};
    #pragma unroll
    for(int i=0;i<10;i++) s[i]+=c[i];
    int idx=0;
    #pragma unroll
    for(int i=0;i<10;i++){
      #pragma unroll
      for(int j=i;j<10;j++){
        M[idx] = fmaf(c[i],c[j],M[idx]);
        idx++;
      }
    }
  }
  #pragma unroll
  for(int i=0;i<10;i++){
    for(int off=32; off>0; off>>=1) s[i] += __shfl_down(s[i], off, 64);
  }
  #pragma unroll
  for(int i=0;i<55;i++){
    for(int off=32; off>0; off>>=1) M[i] += __shfl_down(M[i], off, 64);
  }
  __shared__ float sm[4][65];
  int lane = threadIdx.x & 63, w = threadIdx.x >> 6;
  if(lane==0){
    #pragma unroll
    for(int i=0;i<10;i++) sm[w][i]=s[i];
    #pragma unroll
    for(int i=0;i<55;i++) sm[w][10+i]=M[i];
  }
  __syncthreads();
  if(threadIdx.x<65){
    float v = sm[0][threadIdx.x]+sm[1][threadIdx.x]+sm[2][threadIdx.x]+sm[3][threadIdx.x];
    part1[blockIdx.x*65 + threadIdx.x] = v;
  }
}

// ---------------- kernel 2: finalize BN1 scale/shift ------------------------
__device__ __forceinline__ int tri_idx(int i,int j){
  int a = i<j? i : j;
  int b = i<j? j : i;
  return 10*a - (a*(a-1))/2 + (b-a);
}
__global__ __launch_bounds__(256) void k2_fin(const float* __restrict__ part1, const float* __restrict__ w1,
                       const float* __restrict__ g1, const float* __restrict__ be1,
                       float* __restrict__ stats1){
  __shared__ float P[4][65];
  __shared__ float S[65];
  int t = threadIdx.x; // 256
  for(int idx=t; idx<260; idx+=256){
    int seg = idx/65, v = idx - seg*65;
    float a=0.f;
    for(int b=seg; b<B1G; b+=4) a += part1[b*65+v];
    P[seg][v]=a;
  }
  __syncthreads();
  if(t<65) S[t] = P[0][t]+P[1][t]+P[2][t]+P[3][t];
  __syncthreads();
  if(t<128){
    float wc[10];
    #pragma unroll
    for(int c=0;c<10;c++) wc[c]=w1[c*128+t];
    float md=0.f;
    #pragma unroll
    for(int c=0;c<10;c++) md += S[c]*wc[c];
    const float invR = 1.0f/(float)(NPTS*16);
    md *= invR;
    float q=0.f;
    #pragma unroll
    for(int i=0;i<10;i++){
      float ti=0.f;
      #pragma unroll
      for(int j=0;j<10;j++) ti += S[10+tri_idx(i,j)]*wc[j];
      q = fmaf(ti, wc[i], q);
    }
    q *= invR;
    float var = q - md*md;
    float sc = g1[t]*rsqrtf(var+EPSV);
    float sh = be1[t] - md*sc;            // b1 cancels inside BN
    stats1[t]=sc;
    stats1[128+t]=sh;
  }
}

// ---------------- kernel 2c: W2S = w2 @ ws_top, cb = b2 @ ws_top ------------
// Writes into the part1 region (16512 <= 16640 floats) AFTER k2 consumed it.
__global__ __launch_bounds__(256) void k2c_w2s(const float* __restrict__ w2, const float* __restrict__ wsm,
                        const float* __restrict__ b2, float* __restrict__ w2s){
  int gid = blockIdx.x*256 + threadIdx.x;   // 64 blocks -> 16384 threads
  int k = gid >> 7, e = gid & 127;
  float a = 0.f;
  for(int d=0; d<64; d++) a = fmaf(w2[k*64+d], wsm[d*128+e], a);
  w2s[k*128+e] = a;
  if(gid < 128){
    float cbv = 0.f;
    for(int d=0; d<64; d++) cbv = fmaf(b2[d], wsm[d*128+gid], cbv);
    w2s[16384+gid] = cbv;
  }
}

// ---------------- kernel 3: MFMA block-cooperative pipeline -----------------
// 2 barriers/round. logits = h@W2S + x@ws_bot + cb (p_c never round-trips
// through LDS; value pooling uses fp32 p_c from the lane's own accumulator).
// Register plan vs r6 (which spilled): p loads direct in stage1 (no dbuf),
// x dbuf packed to bf16 right after stage1 (8 u32, not 16 f32), Bwo transient.
__global__ __launch_bounds__(256,4) void k3_main(
    const float* __restrict__ p, const float* __restrict__ x,
    const float* __restrict__ w2, const float* __restrict__ b2,
    const float* __restrict__ wsm, const float* __restrict__ wo,
    const float* __restrict__ w1, const float* __restrict__ stats1,
    const float* __restrict__ w2s,
    float* __restrict__ pre, float* __restrict__ part2)
{
  __shared__ unsigned short s_h [4][16][136];   // h bf16 (interleaved cols), 272B row stride
  __shared__ unsigned short s_x [4][16][72];    // x bf16 (natural cols 0..63), 144B row stride
  __shared__ unsigned short s_ft[16][136];      // feat bf16 (chmap2-interleaved cols)

  const int tid  = threadIdx.x;
  const int w    = tid>>6;
  const int lane = tid&63;
  const int q    = lane>>4;
  const int c    = lane&15;

  // ---- register-resident B fragments (k = kk*32 + q*8 + j) ----------------
  v8s Bw1[2], Bw2[4], BSlo[4], BShi[4], Bbl[2], Bbh[2];
  #pragma unroll
  for(int t=0;t<2;t++){
    F8 f;
    #pragma unroll
    for(int j=0;j<8;j++){
      int k = q*8+j;
      f.s[j] = (unsigned short)(k<10 ? f2bf(w1[k*128 + 32*w + 16*t + c]) : 0);
    }
    Bw1[t]=f.v;
  }
  #pragma unroll
  for(int kk=0;kk<4;kk++){                      // rows chmap'd: s_h is col-interleaved
    F8 f, g, h2;
    #pragma unroll
    for(int j=0;j<8;j++){
      int row = chmap(kk*32+q*8+j);
      f.s[j]  = (unsigned short)f2bf(w2 [row*64  + 16*w + c]);
      g.s[j]  = (unsigned short)f2bf(w2s[row*128 + 16*w + c]);
      h2.s[j] = (unsigned short)f2bf(w2s[row*128 + 64 + 16*w + c]);
    }
    Bw2[kk]=f.v; BSlo[kk]=g.v; BShi[kk]=h2.v;
  }
  #pragma unroll
  for(int kk=0;kk<2;kk++){                      // x-part of ws: natural rows
    F8 f, g;
    #pragma unroll
    for(int j=0;j<8;j++){
      int row = 64 + kk*32+q*8+j;
      f.s[j] = (unsigned short)f2bf(wsm[row*128 + 16*w + c]);
      g.s[j] = (unsigned short)f2bf(wsm[row*128 + 64 + 16*w + c]);
    }
    Bbl[kk]=f.v; Bbh[kk]=g.v;
  }
  const float sc1a = stats1[32*w+c],    sh1a = stats1[128+32*w+c];
  const float sc1b = stats1[32*w+16+c], sh1b = stats1[128+32*w+16+c];
  const float b2v  = b2[16*w+c];
  const float cb_lo = w2s[16384 + 16*w+c];
  const float cb_hi = w2s[16384 + 64+16*w+c];

  float a_s=0.f, a_q=0.f;
  const int base0 = blockIdx.x*64;

  // ---- x staging: per-thread LDS destinations are round-invariant ---------
  unsigned short *xd0, *xd1, *xd2, *xd3;
  {
    int f;
    f = tid;       xd0 = &s_x[f>>8][(f&255)>>4][4*(f&15)];
    f = tid+256;   xd1 = &s_x[f>>8][(f&255)>>4][4*(f&15)];
    f = tid+512;   xd2 = &s_x[f>>8][(f&255)>>4][4*(f&15)];
    f = tid+768;   xd3 = &s_x[f>>8][(f&255)>>4][4*(f&15)];
  }
  // prologue: round-0 x packed to bf16 pairs (8 u32 carried, not 16 f32)
  uint2 xp0, xp1, xp2, xp3;
  {
    const float4* xg = (const float4*)(x + (size_t)base0*1024);
    float4 a0=xg[tid], a1=xg[tid+256], a2=xg[tid+512], a3=xg[tid+768];
    xp0 = make_uint2(packbf(a0.x,a0.y), packbf(a0.z,a0.w));
    xp1 = make_uint2(packbf(a1.x,a1.y), packbf(a1.z,a1.w));
    xp2 = make_uint2(packbf(a2.x,a2.y), packbf(a2.z,a2.w));
    xp3 = make_uint2(packbf(a3.x,a3.y), packbf(a3.z,a3.w));
  }

  for(int r=0;r<16;++r){
    const int base = base0 + 4*r;

    // ---- write packed x regs -> s_x, then issue next round's loads --------
    *(uint2*)xd0 = xp0;
    *(uint2*)xd1 = xp1;
    *(uint2*)xd2 = xp2;
    *(uint2*)xd3 = xp3;
    float4 a0,a1,a2,a3;
    if(r<15){
      const float4* xg = (const float4*)(x + (size_t)(base+4)*1024);
      a0 = xg[tid]; a1 = xg[tid+256]; a2 = xg[tid+512]; a3 = xg[tid+768];
    }

    // ---- stage1: h = concat@w1 -> BN1 -> relu -> s_h (bf16, interleaved) --
    // (hides the x-load latency issued above)
    #pragma unroll
    for(int n0=0;n0<4;n0++){
      const float* pn = p + (size_t)(base+n0)*48;
      float cx=pn[0], cy=pn[1], cz=pn[2];
      float ax=pn[3*c], ay=pn[3*c+1], az=pn[3*c+2];   // lane's point m=c
      float dx=cx-ax, dy=cy-ay, dz=cz-az;
      float dd=sqrtf(dx*dx+dy*dy+dz*dz);
      u32 pk01=packbf(cx,cy), pk23=packbf(cz,ax), pk45=packbf(ay,az),
          pk67=packbf(dx,dy), pk89=packbf(dz,dd);
      F8 fa;
      fa.u[0] = q==0 ? pk01 : (q==1 ? pk89 : 0u);
      fa.u[1] = q==0 ? pk23 : 0u;
      fa.u[2] = q==0 ? pk45 : 0u;
      fa.u[3] = q==0 ? pk67 : 0u;
      v4f z={0.f,0.f,0.f,0.f};
      v4f d0 = __builtin_amdgcn_mfma_f32_16x16x32_bf16(fa.v, Bw1[0], z, 0,0,0);
      v4f d1 = __builtin_amdgcn_mfma_f32_16x16x32_bf16(fa.v, Bw1[1], z, 0,0,0);
      #pragma unroll
      for(int i=0;i<4;i++){
        float v0 = fmaxf(0.f, fmaf(d0[i], sc1a, sh1a));
        float v1 = fmaxf(0.f, fmaf(d1[i], sc1b, sh1b));
        *(u32*)&s_h[n0][4*q+i][32*w+2*c] = packbf(v0, v1);
      }
    }

    // ---- pack next round's x now that loads have landed under stage1 ------
    if(r<15){
      xp0 = make_uint2(packbf(a0.x,a0.y), packbf(a0.z,a0.w));
      xp1 = make_uint2(packbf(a1.x,a1.y), packbf(a1.z,a1.w));
      xp2 = make_uint2(packbf(a2.x,a2.y), packbf(a2.z,a2.w));
      xp3 = make_uint2(packbf(a3.x,a3.y), packbf(a3.z,a3.w));
    }
    __syncthreads();   // barrier1: s_h + s_x ready

    // ---- phase A: p_c, logits, softmax, pool -> s_ft ----------------------
    #pragma unroll
    for(int n0=0;n0<4;n0++){
      const v8s* Ah = (const v8s*)&s_h[n0][c][0];
      const v8s* Ax = (const v8s*)&s_x[n0][c][0];
      v4f acc={0.f,0.f,0.f,0.f}, llo={0.f,0.f,0.f,0.f}, lhi={0.f,0.f,0.f,0.f};
      #pragma unroll
      for(int kk=0;kk<4;kk++){
        v8s a = Ah[kk*4+q];
        acc = __builtin_amdgcn_mfma_f32_16x16x32_bf16(a, Bw2[kk],  acc, 0,0,0);
        llo = __builtin_amdgcn_mfma_f32_16x16x32_bf16(a, BSlo[kk], llo, 0,0,0);
        lhi = __builtin_amdgcn_mfma_f32_16x16x32_bf16(a, BShi[kk], lhi, 0,0,0);
      }
      #pragma unroll
      for(int kk=0;kk<2;kk++){
        v8s a = Ax[kk*4+q];
        llo = __builtin_amdgcn_mfma_f32_16x16x32_bf16(a, Bbl[kk], llo, 0,0,0);
        lhi = __builtin_amdgcn_mfma_f32_16x16x32_bf16(a, Bbh[kk], lhi, 0,0,0);
      }
      float se_lo=0.f, se_hi=0.f, fe_lo=0.f, fe_hi=0.f;
      #pragma unroll
      for(int i=0;i<4;i++){
        float pcv = acc[i] + b2v;                       // fp32 p_c, own channel
        float xv  = bf2f(s_x[n0][4*q+i][16*w+c]);       // x value, own channel
        float El = __expf(llo[i] + cb_lo);
        float Eh = __expf(lhi[i] + cb_hi);
        se_lo += El; fe_lo = fmaf(El, pcv, fe_lo);
        se_hi += Eh; fe_hi = fmaf(Eh, xv,  fe_hi);
      }
      se_lo += __shfl_xor(se_lo,16); se_lo += __shfl_xor(se_lo,32);
      se_hi += __shfl_xor(se_hi,16); se_hi += __shfl_xor(se_hi,32);
      fe_lo += __shfl_xor(fe_lo,16); fe_lo += __shfl_xor(fe_lo,32);
      fe_hi += __shfl_xor(fe_hi,16); fe_hi += __shfl_xor(fe_hi,32);
      if(q==0){
        const int slot = (r&3)*4 + n0;
        *(u32*)&s_ft[slot][32*w+2*c] = packbf(fe_lo*rcpf(se_lo), fe_hi*rcpf(se_hi));
      }
    }
    __syncthreads();   // barrier2: s_ft ready; s_h/s_x free for next round

    // ---- stage5: out = feat@wo for 16 buffered n (every 4 rounds) ---------
    if((r&3)==3){
      v8s Bwo[4];
      #pragma unroll
      for(int kk=0;kk<4;kk++){                  // rows chmap2'd (s_ft layout); L2-hot
        F8 f;
        #pragma unroll
        for(int j=0;j<8;j++) f.s[j]=(unsigned short)f2bf(wo[chmap2(kk*32+q*8+j)*64 + 16*w + c]);
        Bwo[kk]=f.v;
      }
      const v8s* Ar = (const v8s*)&s_ft[c][0];
      v4f o={0.f,0.f,0.f,0.f};
      #pragma unroll
      for(int kk=0;kk<4;kk++)
        o = __builtin_amdgcn_mfma_f32_16x16x32_bf16(Ar[kk*4+q], Bwo[kk], o, 0,0,0);
      const int nb16 = base0 + (r>>2)*16;
      #pragma unroll
      for(int i=0;i<4;i++){
        float val = o[i];
        pre[(size_t)(nb16 + 4*q + i)*64 + 16*w + c] = val;
        a_s += val;
        a_q = fmaf(val,val,a_q);
      }
    }
  }

  // ---- BN2 partials: reduce over quads (same d = 16w+c across q) ----------
  a_s += __shfl_xor(a_s, 16, 64); a_s += __shfl_xor(a_s, 32, 64);
  a_q += __shfl_xor(a_q, 16, 64); a_q += __shfl_xor(a_q, 32, 64);
  if(q==0){
    part2[blockIdx.x*128 + 16*w + c]      = a_s;
    part2[blockIdx.x*128 + 64 + 16*w + c] = a_q;
  }
}

// ---------------- kernel 4: finalize BN2 scale/shift ------------------------
__global__ __launch_bounds__(1024) void k4_fin(const float* __restrict__ part2, const float* __restrict__ g2,
                       const float* __restrict__ be2, float* __restrict__ stats2){
  __shared__ float sm[16][128];
  int t = threadIdx.x; // 1024
  int d = t & 63, seg = t >> 6;   // 16 segs
  float s=0.f, qq=0.f;
  for(int i=0;i<B3G/16;i++){
    int b = seg + 16*i;
    s  += part2[b*128+d];
    qq += part2[b*128+64+d];
  }
  sm[seg][d]    = s;
  sm[seg][64+d] = qq;
  __syncthreads();
  if(t<64){
    float S=0.f, Q=0.f;
    #pragma unroll
    for(int k=0;k<16;k++){ S += sm[k][t]; Q += sm[k][64+t]; }
    float mu  = S/(float)NPTS;
    float var = Q/(float)NPTS - mu*mu;
    float sc = g2[t]*rsqrtf(var+EPSV);
    float sh = be2[t] - mu*sc;            // bo cancels inside BN
    stats2[t]=sc;
    stats2[64+t]=sh;
  }
}

// ---------------- kernel 5: apply BN2 + relu --------------------------------
__global__ __launch_bounds__(256) void k5_apply(const float* __restrict__ pre,
                                                const float* __restrict__ stats2,
                                                float* __restrict__ out){
  int i = blockIdx.x*256 + threadIdx.x;      // float4 index; 1,048,576 total
  float4 v = ((const float4*)pre)[i];
  int d4 = i & 15;
  float4 sc = ((const float4*)stats2)[d4];
  float4 sh = ((const float4*)(stats2+64))[d4];
  float4 o;
  o.x = fmaxf(0.f, fmaf(v.x,sc.x,sh.x));
  o.y = fmaxf(0.f, fmaf(v.y,sc.y,sh.y));
  o.z = fmaxf(0.f, fmaf(v.z,sc.z,sh.z));
  o.w = fmaxf(0.f, fmaf(v.w,sc.w,sh.w));
  ((float4*)out)[i] = o;
}

extern "C" void kernel_launch(void* const* d_in, const int* in_sizes, int n_in,
                              void* d_out, int out_size, void* d_ws, size_t ws_size,
                              hipStream_t stream){
  (void)in_sizes; (void)n_in; (void)out_size; (void)ws_size;
  const float* p   = (const float*)d_in[0];
  const float* x   = (const float*)d_in[1];
  const float* w1  = (const float*)d_in[2];
  // d_in[3] = b1  : cancels inside BN1
  const float* g1  = (const float*)d_in[4];
  const float* be1 = (const float*)d_in[5];
  const float* w2  = (const float*)d_in[6];
  const float* b2  = (const float*)d_in[7];
  const float* wsm = (const float*)d_in[8];
  const float* wo  = (const float*)d_in[9];
  // d_in[10] = bo : cancels inside BN2
  const float* g2  = (const float*)d_in[11];
  const float* be2 = (const float*)d_in[12];

  float* wsf    = (float*)d_ws;
  float* part1  = wsf + OFF_P1;     // reused as W2S/cb after k2
  float* stats1 = wsf + OFF_S1;
  float* part2  = wsf + OFF_P2;
  float* stats2 = wsf + OFF_S2;
  float* pre    = wsf + OFF_PRE;
  float* out    = (float*)d_out;

  k1_stats<<<B1G,256,0,stream>>>(p, part1);
  k2_fin  <<<1,256,0,stream>>>(part1, w1, g1, be1, stats1);
  k2c_w2s <<<64,256,0,stream>>>(w2, wsm, b2, part1);
  k3_main <<<B3G,256,0,stream>>>(p,x,w2,b2,wsm,wo,w1,stats1,part1,pre,part2);
  k4_fin  <<<1,1024,0,stream>>>(part2,g2,be2,stats2);
  k5_apply<<<4096,256,0,stream>>>(pre,stats2,out);
}